// Round 7
// baseline (298.657 us; speedup 1.0000x reference)
//
#include <hip/hip_runtime.h>
#include <math.h>

// Problem constants: B=8, C=256, H=W=128
#define NPLANE 2048
#define HW     16384
#define WW     128
#define SLOPE  0.01f
#define EPS    1e-5f

typedef float v4f __attribute__((ext_vector_type(4)));  // native vec for nontemporal store

struct W9 { float w0,w1,w2,w3,w4,w5,w6,w7,w8; };

// Load one image row segment (4 cols) + left/right neighbors via cross-lane
// shuffle.  Each 32-lane half-wave spans one full row (32*4=128 cols), so the
// lane-31/32 shuffle boundary coincides with the column zero-pad boundary --
// one mask handles both.
__device__ __forceinline__ void load_row(const float* __restrict__ xp, int r,
                                         int c4, int lane32,
                                         float4& m, float& L, float& R) {
    int rc = r;
    if (rc < 0) rc = 0;
    if (rc > 127) rc = 127;
    const float va = (r == rc) ? 1.f : 0.f;        // zero-pad rows -1 / 128
    float4 v = *(const float4*)(xp + rc * WW + c4);
    m.x = v.x * va; m.y = v.y * va; m.z = v.z * va; m.w = v.w * va;
    L = __shfl_up(m.w, 1, 64);
    if (lane32 == 0) L = 0.f;                      // col -1 zero-pad
    R = __shfl_down(m.x, 1, 64);
    if (lane32 == 31) R = 0.f;                     // col 128 zero-pad
}

// ---------------------------------------------------------------------------
// Kernel 1 (k_conv): THE ONLY HBM READ OF x IN THE PIPELINE.
// Streams each plane once computing: plane mean p (attention input), raw
// depthwise-conv values (stored UN-normalized to out -- plain stores so the
// lines write-allocate and stay dirty in the 256 MB L3; 131 MB fits), and
// conv sum/sumsq for the folded instance norm.
// Rationale (round-5 diagnosis): any structure that re-reads x during the
// store pass has a 265 MB combined footprint -> L3 thrash -> ~400 MB HBM.
// Writing raw conv and re-reading IT keeps the re-read 20 us fresh and lets
// the in-place rewrite in k_norm re-dirty the same lines, so the
// intermediate data mostly never drains to HBM.
// Thread t: columns [4*(t&31), +4), rows [16*(t>>5), +16), sliding window.
// ~35 VGPR, full 8 blocks/CU occupancy.
// ---------------------------------------------------------------------------
__global__ __launch_bounds__(256, 8) void k_conv(const float* __restrict__ x,
                                                 const float* __restrict__ rw,
                                                 float* __restrict__ p,
                                                 float* __restrict__ cstats,
                                                 float* __restrict__ out) {
    const int plane = blockIdx.x;
    const int ch = plane & 255;
    const float* xp = x + (size_t)plane * HW;
    float* op = out + (size_t)plane * HW;
    const int lane32 = threadIdx.x & 31;
    const int c4 = lane32 * 4;
    const int r0 = (threadIdx.x >> 5) * 16;

    const W9 w = { rw[ch*9+0], rw[ch*9+1], rw[ch*9+2],
                   rw[ch*9+3], rw[ch*9+4], rw[ch*9+5],
                   rw[ch*9+6], rw[ch*9+7], rw[ch*9+8] };

    float4 m0, m1, m2;
    float L0, R0, L1, R1, L2, R2;
    load_row(xp, r0 - 1, c4, lane32, m0, L0, R0);
    load_row(xp, r0,     c4, lane32, m1, L1, R1);

    float xs = 0.f, s = 0.f, sq = 0.f;
#pragma unroll 4
    for (int j = 0; j < 16; ++j) {
        load_row(xp, r0 + j + 1, c4, lane32, m2, L2, R2);
        float o0 = w.w0*L0   + w.w1*m0.x + w.w2*m0.y
                 + w.w3*L1   + w.w4*m1.x + w.w5*m1.y
                 + w.w6*L2   + w.w7*m2.x + w.w8*m2.y;
        float o1 = w.w0*m0.x + w.w1*m0.y + w.w2*m0.z
                 + w.w3*m1.x + w.w4*m1.y + w.w5*m1.z
                 + w.w6*m2.x + w.w7*m2.y + w.w8*m2.z;
        float o2 = w.w0*m0.y + w.w1*m0.z + w.w2*m0.w
                 + w.w3*m1.y + w.w4*m1.z + w.w5*m1.w
                 + w.w6*m2.y + w.w7*m2.z + w.w8*m2.w;
        float o3 = w.w0*m0.z + w.w1*m0.w + w.w2*R0
                 + w.w3*m1.z + w.w4*m1.w + w.w5*R1
                 + w.w6*m2.z + w.w7*m2.w + w.w8*R2;
        // raw conv -> out (PLAIN store: we WANT write-allocate + L3 residency)
        float4 res; res.x = o0; res.y = o1; res.z = o2; res.w = o3;
        *(float4*)(op + (r0 + j) * WW + c4) = res;
        s  += (o0 + o1) + (o2 + o3);
        sq += o0*o0 + o1*o1 + o2*o2 + o3*o3;
        xs += (m1.x + m1.y) + (m1.z + m1.w);   // row r counted exactly once
        m0 = m1; L0 = L1; R0 = R1; m1 = m2; L1 = L2; R1 = R2;
    }

#pragma unroll
    for (int off = 32; off; off >>= 1) {
        xs += __shfl_down(xs, off, 64);
        s  += __shfl_down(s,  off, 64);
        sq += __shfl_down(sq, off, 64);
    }
    __shared__ float red[12];
    const int wave = threadIdx.x >> 6, lane = threadIdx.x & 63;
    if (lane == 0) { red[wave] = xs; red[4+wave] = s; red[8+wave] = sq; }
    __syncthreads();
    if (threadIdx.x == 0) {
        p[plane]            = ((red[0]+red[1]) + (red[2]+red[3])) * (1.f/(float)HW);
        cstats[plane*2]     = (red[4]+red[5]) + (red[6]+red[7]);
        cstats[plane*2 + 1] = (red[8]+red[9]) + (red[10]+red[11]);
    }
}

// ---------------------------------------------------------------------------
// Kernel 2 (k_norm): attention MLP (kernel boundary guarantees all p of the
// batch are complete) + in-place elementwise affine + leaky over out.
//   final = a*(conv - mean_c) * rsqrt(a^2*var_c + eps)  (refine_b cancels)
// Reads lines k_conv wrote ~20 us earlier (131 MB < 256 MB L3, nothing
// intervened -> hits), re-dirties the SAME lines in place -> only the final
// values ever drain to HBM.  Pure stream, ~20 VGPR.
// ---------------------------------------------------------------------------
__global__ __launch_bounds__(256, 8) void k_norm(const float* __restrict__ w1,
                                                 const float* __restrict__ w2,
                                                 const float* __restrict__ p,
                                                 const float* __restrict__ cstats,
                                                 float* __restrict__ out) {
    __shared__ float hs[64];
    __shared__ float sh_mean, sh_scale;
    const int plane = blockIdx.x;
    const int b = plane >> 8, ch = plane & 255;

    // attention hidden layer: hs[j] = leaky(dot(p[b,:], w1[j,:])), 4 thr/j
    {
        const int j = threadIdx.x >> 2, part = threadIdx.x & 3;
        const float4* pr = (const float4*)(p  + b * 256 + part * 64);
        const float4* wr = (const float4*)(w1 + j * 256 + part * 64);
        float acc = 0.f;
#pragma unroll
        for (int k = 0; k < 16; ++k) {
            float4 pv = pr[k], wv = wr[k];
            acc += pv.x*wv.x + pv.y*wv.y + pv.z*wv.z + pv.w*wv.w;
        }
        acc += __shfl_xor(acc, 1, 64);
        acc += __shfl_xor(acc, 2, 64);
        if (part == 0) hs[j] = acc > 0.f ? acc : SLOPE * acc;
    }
    __syncthreads();
    if (threadIdx.x < 64) {
        float v = w2[ch * 64 + threadIdx.x] * hs[threadIdx.x];
#pragma unroll
        for (int off = 32; off; off >>= 1) v += __shfl_down(v, off, 64);
        if (threadIdx.x == 0) {
            const float a  = 1.f / (1.f + expf(-v));
            const float mc = cstats[plane*2] * (1.f/(float)HW);
            const float vc = cstats[plane*2 + 1] * (1.f/(float)HW) - mc * mc;
            sh_mean  = mc;
            sh_scale = a * rsqrtf(a * a * vc + EPS);
        }
    }
    __syncthreads();
    const float mean_c = sh_mean, scale = sh_scale;

    // in-place affine + leaky: 16 float4 per thread, fully coalesced
    float4* op = (float4*)(out + (size_t)plane * HW);
#pragma unroll 4
    for (int i = 0; i < 16; ++i) {
        float4 r = op[i * 256 + threadIdx.x];
        v4f o;
        float t0 = scale * (r.x - mean_c); o.x = t0 > 0.f ? t0 : SLOPE * t0;
        float t1 = scale * (r.y - mean_c); o.y = t1 > 0.f ? t1 : SLOPE * t1;
        float t2 = scale * (r.z - mean_c); o.z = t2 > 0.f ? t2 : SLOPE * t2;
        float t3 = scale * (r.w - mean_c); o.w = t3 > 0.f ? t3 : SLOPE * t3;
        __builtin_nontemporal_store(o, (v4f*)(op + i * 256 + threadIdx.x));
    }
}

// ---------------------------------------------------------------------------
extern "C" void kernel_launch(void* const* d_in, const int* in_sizes, int n_in,
                              void* d_out, int out_size, void* d_ws, size_t ws_size,
                              hipStream_t stream) {
    const float* x  = (const float*)d_in[0];
    const float* w1 = (const float*)d_in[1];   // [64,256]
    const float* w2 = (const float*)d_in[2];   // [256,64]
    const float* rw = (const float*)d_in[3];   // [256,1,3,3]
    // d_in[4] (refine_b) cancels exactly in instance norm -- unused.
    float* out = (float*)d_out;

    float* p      = (float*)d_ws;       // 2048 floats (per-plane means)
    float* cstats = p + NPLANE;         // 4096 floats (conv sum, sumsq)

    k_conv<<<NPLANE, 256, 0, stream>>>(x, rw, p, cstats, out);
    k_norm<<<NPLANE, 256, 0, stream>>>(w1, w2, p, cstats, out);
}